// Round 2
// 4595.453 us; speedup vs baseline: 1.1949x; 1.1949x over previous
//
#include <hip/hip_runtime.h>
#include <hip/hip_bf16.h>
#include <stdint.h>

// WiredRNN: h_{t+1} = tanh([h_t | x_t] @ [Wr;Wi] + b), B=32, L=8192, C=128, U=256, OUT=64.
// R5 structure (resubmit — prior round failed on container infra, not kernel):
//   1) xw_gemm_kernel: full-chip GEMM XW[b,t,u] = x[b,t,:] @ (W_in*M_in) + bias  -> d_ws (f16)
//   2) rnn_scan_xw: 32 persistent WGs (one per batch), 512 threads (8 waves).
//      Thread (wave w, lane l): u = w*32 + (l&31), K-half kc = l>>5 (64 fdot2, 4 acc chains).
//      Cross-half reduce = single in-wave __shfl_xor(s,32)  -> no partial[] array, zero LDS
//      bank conflicts. Double-buffered h state vec[2][256] -> ONE barrier per step (was 2).
//      xw prefetched one step ahead (clamped), latency hidden under the dot.
// Fallback (ws_size too small): R3's proven K=384 scan.

#define NB 32
#define SL 8192
#define NC 128
#define NU 256
#define NO 64
#define NK 384
#define GR 64          // rows per GEMM workgroup

typedef _Float16 h16;
typedef __attribute__((ext_vector_type(2))) _Float16 h16x2;

__device__ __forceinline__ float fdot2f(h16x2 a, h16x2 b, float c) {
#if __has_builtin(__builtin_amdgcn_fdot2)
    return __builtin_amdgcn_fdot2(a, b, c, false);
#else
    return c + (float)a[0] * (float)b[0] + (float)a[1] * (float)b[1];
#endif
}

// tanh(x) = 1 - 2/(e^{2x}+1);  e^{2x} = 2^{x*2*log2(e)}.  v_exp_f32 + v_rcp_f32.
__device__ __forceinline__ float ftanh(float x) {
#if __has_builtin(__builtin_amdgcn_exp2f) && __has_builtin(__builtin_amdgcn_rcpf)
    float e = __builtin_amdgcn_exp2f(x * 2.8853900817779268f);
    return 1.0f - 2.0f * __builtin_amdgcn_rcpf(e + 1.0f);
#else
    return tanhf(x);
#endif
}

// ---------------- XW precompute GEMM ----------------
// grid = (B*SL)/GR = 4096 WGs x 256 threads. Thread u holds Wi column u (masked, f16 pairs)
// in registers; x tile staged in LDS as f16; 64 fdot2 per row, broadcast LDS reads.
__global__ __launch_bounds__(256, 4) void xw_gemm_kernel(
    const float* __restrict__ x,      // [B*SL, NC]
    const float* __restrict__ W_in,   // [NC, NU]
    const float* __restrict__ bias,   // [NU]
    const float* __restrict__ M_in,   // [NC, NU]
    h16* __restrict__ xw)             // [B*SL, NU]
{
    const int u = threadIdx.x;
    const long row0 = (long)blockIdx.x * GR;
    __shared__ h16 xs[GR * NC];       // 16 KB

    // stage x tile (coalesced fp32 -> f16)
    for (int i = u; i < GR * NC; i += 256)
        xs[i] = (h16)x[row0 * NC + i];

    // Wi column u, masked, packed pairs (coalesced global reads across lanes)
    h16x2 wc[NC / 2];
#pragma unroll
    for (int j = 0; j < NC / 2; ++j) {
        const int k0 = 2 * j, k1 = 2 * j + 1;
        float w0 = W_in[k0 * NU + u] * M_in[k0 * NU + u];
        float w1 = W_in[k1 * NU + u] * M_in[k1 * NU + u];
        h16x2 t; t[0] = (h16)w0; t[1] = (h16)w1;
        wc[j] = t;
    }
    const float bs = bias[u];
    __syncthreads();

    for (int r = 0; r < GR; ++r) {
        const h16x2* xv = (const h16x2*)&xs[r * NC];   // wave-uniform -> broadcast reads
        float acc = bs;
#pragma unroll
        for (int j = 0; j < NC / 2; ++j)
            acc = fdot2f(xv[j], wc[j], acc);
        xw[(row0 + r) * NU + u] = (h16)acc;
    }
}

// ---------------- recurrent scan (512 thr, in-wave reduce, 1 barrier/step) ----------------
__global__ __launch_bounds__(512, 2) void rnn_scan_xw(
    const float* __restrict__ W_rec,  // [NU, NU]
    const float* __restrict__ M_rec,  // [NU, NU]
    const h16* __restrict__ xw,       // [B*SL, NU] (bias folded in)
    float* __restrict__ out)          // [B*SL*NO] readout ++ [B*NU] h_last
{
    const int tid  = threadIdx.x;
    const int b    = blockIdx.x;
    const int lane = tid & 63;
    const int wv   = tid >> 6;             // 0..7
    const int u    = (wv << 5) | (lane & 31);  // 0..255 (lanes 0-31 and 32-63 share u range)
    const int kc   = lane >> 5;            // 0 or 1 -> K-half
    const int ks   = kc << 7;              // 0 or 128

    __shared__ __align__(16) h16 vec[2][NU];   // double-buffered h state (1 KB)

    // masked recurrent weights for (u, k in [ks, ks+128)), packed f16 pairs: 64 VGPRs
    h16x2 w[64];
#pragma unroll
    for (int j = 0; j < 64; ++j) {
        const int k0 = ks + 2 * j, k1 = k0 + 1;
        float w0 = W_rec[k0 * NU + u] * M_rec[k0 * NU + u];
        float w1 = W_rec[k1 * NU + u] * M_rec[k1 * NU + u];
        h16x2 t; t[0] = (h16)w0; t[1] = (h16)w1;
        w[j] = t;
    }

    if (tid < NU) vec[0][tid] = (h16)0.f;
    __syncthreads();

    const h16* __restrict__ xwb = xw + (long)b * SL * NU;
    long off = u;
    float xwv = (float)xwb[off];           // xw for t=0 (same value on both kc lanes)

    float* const outb = out + (long)b * SL * NO;
    const int uo = u - (NU - NO);          // >=0 only for motor neurons

    for (int t = 0; t < SL; ++t) {
        // prefetch xw for t+1 (clamped: last iter re-reads t, value unused)
        const long offn = (t + 1 < SL) ? off + (long)NU : off;
        const float xwn = (float)xwb[offn];

        // 64 fdot2 over this thread's K-half; LDS reads are wave-broadcast (conflict-free)
        const h16x2* v2 = (const h16x2*)(&vec[t & 1][ks]);
        float a0 = 0.f, a1 = 0.f, a2 = 0.f, a3 = 0.f;
#pragma unroll
        for (int j = 0; j < 16; ++j) {
            a0 = fdot2f(v2[4 * j + 0], w[4 * j + 0], a0);
            a1 = fdot2f(v2[4 * j + 1], w[4 * j + 1], a1);
            a2 = fdot2f(v2[4 * j + 2], w[4 * j + 2], a2);
            a3 = fdot2f(v2[4 * j + 3], w[4 * j + 3], a3);
        }
        float s = (a0 + a1) + (a2 + a3);
        if (kc) s += xwv;                  // fold xw into one half before the exchange
        s += __shfl_xor(s, 32, 64);        // cross-half reduce, in-wave (no LDS partials)

        const float hn = ftanh(s);
        if (kc == 0) {
            vec[(t + 1) & 1][u] = (h16)hn;             // state update into next buffer
            if (t == SL - 1)
                out[(long)NB * SL * NO + (long)b * NU + u] = hn;   // h_last
        } else if (uo >= 0) {
            outb[(long)t * NO + uo] = hn;              // readout (motor neurons)
        }
        __syncthreads();                   // ONE barrier/step: separates rd(t)/wr(t+1) hazards
        off = offn; xwv = xwn;
    }
}

// ---------------- fallback (R3, proven): K=384 scan reading x directly ----------------
__global__ __launch_bounds__(1024, 4) void rnn_scan_fallback(
    const float* __restrict__ x,
    const float* __restrict__ W_in,
    const float* __restrict__ W_rec,
    const float* __restrict__ bias,
    const float* __restrict__ M_in,
    const float* __restrict__ M_rec,
    float* __restrict__ out)
{
    const int tid = threadIdx.x;
    const int b   = blockIdx.x;
    const int u   = tid & (NU - 1);
    const int kc  = tid >> 8;
    const int ks  = kc * 96;

    __shared__ __align__(16) h16 vec[NK];
    __shared__ float partial[4][NU];

    h16x2 w[48];
#pragma unroll
    for (int j = 0; j < 48; ++j) {
        const int k0 = ks + 2 * j, k1 = k0 + 1;
        float w0, w1;
        if (k0 < NU) w0 = W_rec[k0 * NU + u] * M_rec[k0 * NU + u];
        else         w0 = W_in[(k0 - NU) * NU + u] * M_in[(k0 - NU) * NU + u];
        if (k1 < NU) w1 = W_rec[k1 * NU + u] * M_rec[k1 * NU + u];
        else         w1 = W_in[(k1 - NU) * NU + u] * M_in[(k1 - NU) * NU + u];
        h16x2 t; t[0] = (h16)w0; t[1] = (h16)w1;
        w[j] = t;
    }
    const float breg = (tid < NU) ? bias[u] : 0.0f;
    const long xbase = (long)b * SL * NC;

    if (tid < NU) vec[tid] = (h16)0.f;
    else if (tid < NU + NC) vec[tid] = (h16)x[xbase + (tid - NU)];
    __syncthreads();

    const bool xthr = (tid >= NU) && (tid < NU + NC);
    for (int t = 0; t < SL; ++t) {
        float xr = 0.f;
        if (xthr && (t + 1 < SL)) xr = x[xbase + (long)(t + 1) * NC + (tid - NU)];

        const h16x2* v2 = (const h16x2*)(&vec[ks]);
        float acc = 0.f;
#pragma unroll
        for (int j = 0; j < 48; ++j) acc = fdot2f(v2[j], w[j], acc);
        partial[kc][u] = acc;
        __syncthreads();

        if (tid < NU) {
            float s = partial[0][u] + partial[1][u] + partial[2][u] + partial[3][u] + breg;
            float hn = ftanh(s);
            vec[u] = (h16)hn;
            if (u >= NU - NO) out[((long)b * SL + t) * NO + (u - (NU - NO))] = hn;
            if (t == SL - 1)  out[(long)NB * SL * NO + (long)b * NU + u] = hn;
        } else if (xthr && (t + 1 < SL)) {
            vec[tid] = (h16)xr;
        }
        __syncthreads();
    }
}

extern "C" void kernel_launch(void* const* d_in, const int* in_sizes, int n_in,
                              void* d_out, int out_size, void* d_ws, size_t ws_size,
                              hipStream_t stream) {
    (void)in_sizes; (void)n_in; (void)out_size;
    const float* x     = (const float*)d_in[0];
    const float* W_in  = (const float*)d_in[1];
    const float* W_rec = (const float*)d_in[2];
    const float* bias  = (const float*)d_in[3];
    const float* M_in  = (const float*)d_in[4];
    const float* M_rec = (const float*)d_in[5];
    float* out = (float*)d_out;

    const size_t xw_bytes = (size_t)NB * SL * NU * sizeof(h16);   // 134,217,728
    if (ws_size >= xw_bytes) {
        h16* xw = (h16*)d_ws;
        xw_gemm_kernel<<<dim3((NB * SL) / GR), dim3(256), 0, stream>>>(x, W_in, bias, M_in, xw);
        rnn_scan_xw<<<dim3(NB), dim3(512), 0, stream>>>(W_rec, M_rec, xw, out);
    } else {
        rnn_scan_fallback<<<dim3(NB), dim3(1024), 0, stream>>>(x, W_in, W_rec, bias, M_in, M_rec, out);
    }
}

// Round 5
// 4532.031 us; speedup vs baseline: 1.2116x; 1.0140x over previous
//
#include <hip/hip_runtime.h>
#include <hip/hip_bf16.h>
#include <stdint.h>

// WiredRNN: h_{t+1} = tanh([h_t | x_t] @ [Wr;Wi] + b), B=32, L=8192, C=128, U=256, OUT=64.
// R7 structure (replaces R6's raw-barrier approach, which is suspect for the repeated
// container failures; R7 uses ONLY __syncthreads and amortizes its vmcnt(0) drain):
//   1) xw_gemm_kernel: full-chip GEMM XW = x @ (W_in*M_in) + bias -> d_ws (f16), 4 ILP chains.
//   2) rnn_scan_xw: 32 persistent WGs, 512 threads (8 waves). Per thread: u = w*32+(l&31),
//      K-half kc = l>>5, 64 fdot2, in-wave __shfl_xor(s,32) reduce, double-buffered vec[2][256],
//      ONE __syncthreads per step.
//      KEY (R7): xw staged in 16-step chunks through double-buffered LDS. Chunk n+1 loaded
//      as one int4/thread at chunk start (drained by the first per-step barrier -> ~900cy
//      exposed ONCE per 16 steps), held in regs, ds_written to LDS at step 15. Per-step xw
//      access is a 2B LDS read; readout stores buffered in regs (static idx via full unroll)
//      and flushed once per chunk. So 15 of 16 barriers drain an empty vmem queue.
// Fallback (ws_size too small): R3's proven K=384 scan.

#define NB 32
#define SL 8192
#define NC 128
#define NU 256
#define NO 64
#define NK 384
#define GR 64          // rows per GEMM workgroup
#define TC 16          // scan steps per xw chunk
#define NCHUNK (SL / TC)

typedef _Float16 h16;
typedef __attribute__((ext_vector_type(2))) _Float16 h16x2;

__device__ __forceinline__ float fdot2f(h16x2 a, h16x2 b, float c) {
#if __has_builtin(__builtin_amdgcn_fdot2)
    return __builtin_amdgcn_fdot2(a, b, c, false);
#else
    return c + (float)a[0] * (float)b[0] + (float)a[1] * (float)b[1];
#endif
}

// tanh(x) = 1 - 2/(e^{2x}+1);  e^{2x} = 2^{x*2*log2(e)}.  v_exp_f32 + v_rcp_f32.
__device__ __forceinline__ float ftanh(float x) {
#if __has_builtin(__builtin_amdgcn_exp2f) && __has_builtin(__builtin_amdgcn_rcpf)
    float e = __builtin_amdgcn_exp2f(x * 2.8853900817779268f);
    return 1.0f - 2.0f * __builtin_amdgcn_rcpf(e + 1.0f);
#else
    return tanhf(x);
#endif
}

// ---------------- XW precompute GEMM ----------------
// grid = (B*SL)/GR = 4096 WGs x 256 threads. Thread u holds Wi column u (masked, f16 pairs)
// in registers; x tile staged in LDS as f16; 64 fdot2 per row (4 ILP chains), broadcast reads.
__global__ __launch_bounds__(256, 4) void xw_gemm_kernel(
    const float* __restrict__ x,      // [B*SL, NC]
    const float* __restrict__ W_in,   // [NC, NU]
    const float* __restrict__ bias,   // [NU]
    const float* __restrict__ M_in,   // [NC, NU]
    h16* __restrict__ xw)             // [B*SL, NU]
{
    const int u = threadIdx.x;
    const long row0 = (long)blockIdx.x * GR;
    __shared__ h16 xs[GR * NC];       // 16 KB

    // stage x tile (coalesced fp32 -> f16)
    for (int i = u; i < GR * NC; i += 256)
        xs[i] = (h16)x[row0 * NC + i];

    // Wi column u, masked, packed pairs (coalesced global reads across lanes)
    h16x2 wc[NC / 2];
#pragma unroll
    for (int j = 0; j < NC / 2; ++j) {
        const int k0 = 2 * j, k1 = 2 * j + 1;
        float w0 = W_in[k0 * NU + u] * M_in[k0 * NU + u];
        float w1 = W_in[k1 * NU + u] * M_in[k1 * NU + u];
        h16x2 t; t[0] = (h16)w0; t[1] = (h16)w1;
        wc[j] = t;
    }
    const float bs = bias[u];
    __syncthreads();

    for (int r = 0; r < GR; ++r) {
        const h16x2* xv = (const h16x2*)&xs[r * NC];   // wave-uniform -> broadcast reads
        float a0 = bs, a1 = 0.f, a2 = 0.f, a3 = 0.f;   // 4 ILP chains
#pragma unroll
        for (int j = 0; j < 16; ++j) {
            a0 = fdot2f(xv[4 * j + 0], wc[4 * j + 0], a0);
            a1 = fdot2f(xv[4 * j + 1], wc[4 * j + 1], a1);
            a2 = fdot2f(xv[4 * j + 2], wc[4 * j + 2], a2);
            a3 = fdot2f(xv[4 * j + 3], wc[4 * j + 3], a3);
        }
        xw[(row0 + r) * NU + u] = (h16)((a0 + a1) + (a2 + a3));
    }
}

// ---------------- recurrent scan (512 thr, chunked LDS xw, 1 barrier/step) ----------------
__global__ __launch_bounds__(512, 2) void rnn_scan_xw(
    const float* __restrict__ W_rec,  // [NU, NU]
    const float* __restrict__ M_rec,  // [NU, NU]
    const h16* __restrict__ xw,       // [B*SL, NU] (bias folded in)
    float* __restrict__ out)          // [B*SL*NO] readout ++ [B*NU] h_last
{
    const int tid  = threadIdx.x;
    const int b    = blockIdx.x;
    const int lane = tid & 63;
    const int wv   = tid >> 6;             // 0..7
    const int u    = (wv << 5) | (lane & 31);  // 0..255
    const int kc   = lane >> 5;            // 0 or 1 -> K-half
    const int ks   = kc << 7;              // 0 or 128

    __shared__ __align__(16) h16 vec[2][NU];         // double-buffered h state (1 KB)
    __shared__ __align__(16) h16 xwc[2][TC][NU];     // double-buffered xw chunks (16 KB)

    // masked recurrent weights for (u, k in [ks, ks+128)), packed f16 pairs: 64 VGPRs
    h16x2 w[64];
#pragma unroll
    for (int j = 0; j < 64; ++j) {
        const int k0 = ks + 2 * j, k1 = k0 + 1;
        float w0 = W_rec[k0 * NU + u] * M_rec[k0 * NU + u];
        float w1 = W_rec[k1 * NU + u] * M_rec[k1 * NU + u];
        h16x2 t; t[0] = (h16)w0; t[1] = (h16)w1;
        w[j] = t;
    }

    const h16* __restrict__ xwb = xw + (long)b * SL * NU;
    float* const outb = out + (long)b * SL * NO;
    const int uo = u - (NU - NO);          // >=0 only for motor neurons

    // prologue: chunk 0 -> LDS buffer 0; h0 = 0
    {
        const int4 c0 = ((const int4*)xwb)[tid];      // 512 thr x 16B = 8KB, coalesced
        if (tid < NU) vec[0][tid] = (h16)0.f;
        ((int4*)&xwc[0][0][0])[tid] = c0;             // compiler waits vmcnt before ds_write
        __syncthreads();
    }

    for (int tc = 0; tc < NCHUNK; ++tc) {
        const int cb = tc & 1;
        const bool havenext = (tc + 1 < NCHUNK);
        int4 creg;
        if (havenext)                                  // issue chunk tc+1 load; drained by the
            creg = ((const int4*)(xwb + (long)(tc + 1) * TC * NU))[tid];  // first barrier below
        float sbuf[TC];                                // statically indexed (full unroll)

#pragma unroll
        for (int j = 0; j < TC; ++j) {
            // 64 fdot2 over this thread's K-half; reads are wave-broadcast (conflict-free)
            const h16x2* v2 = (const h16x2*)(&vec[j & 1][ks]);
            float a0 = 0.f, a1 = 0.f, a2 = 0.f, a3 = 0.f;
#pragma unroll
            for (int q = 0; q < 16; ++q) {
                a0 = fdot2f(v2[4 * q + 0], w[4 * q + 0], a0);
                a1 = fdot2f(v2[4 * q + 1], w[4 * q + 1], a1);
                a2 = fdot2f(v2[4 * q + 2], w[4 * q + 2], a2);
                a3 = fdot2f(v2[4 * q + 3], w[4 * q + 3], a3);
            }
            float s = (a0 + a1) + (a2 + a3);
            if (kc) s += (float)xwc[cb][j][u];         // xw from LDS (2B read)
            s += __shfl_xor(s, 32, 64);                // cross-half reduce, in-wave

            const float hn = ftanh(s);
            if (kc == 0) vec[(j + 1) & 1][u] = (h16)hn;    // state into next buffer
            sbuf[j] = hn;

            if (j == TC - 1) {
                // park next chunk in LDS (vmcnt long satisfied); barrier below orders it
                if (havenext) ((int4*)&xwc[cb ^ 1][0][0])[tid] = creg;
                // flush 16 buffered readout values (motor neurons)
                if (kc == 1 && uo >= 0) {
#pragma unroll
                    for (int jj = 0; jj < TC; ++jj)
                        outb[(long)(tc * TC + jj) * NO + uo] = sbuf[jj];
                }
                if (tc == NCHUNK - 1 && kc == 0)
                    out[(long)NB * SL * NO + (long)b * NU + u] = hn;   // h_last
            }
            __syncthreads();               // ONE barrier/step; vmem queue empty 15/16 steps
        }
    }
}

// ---------------- fallback (R3, proven): K=384 scan reading x directly ----------------
__global__ __launch_bounds__(1024, 4) void rnn_scan_fallback(
    const float* __restrict__ x,
    const float* __restrict__ W_in,
    const float* __restrict__ W_rec,
    const float* __restrict__ bias,
    const float* __restrict__ M_in,
    const float* __restrict__ M_rec,
    float* __restrict__ out)
{
    const int tid = threadIdx.x;
    const int b   = blockIdx.x;
    const int u   = tid & (NU - 1);
    const int kc  = tid >> 8;
    const int ks  = kc * 96;

    __shared__ __align__(16) h16 vec[NK];
    __shared__ float partial[4][NU];

    h16x2 w[48];
#pragma unroll
    for (int j = 0; j < 48; ++j) {
        const int k0 = ks + 2 * j, k1 = k0 + 1;
        float w0, w1;
        if (k0 < NU) w0 = W_rec[k0 * NU + u] * M_rec[k0 * NU + u];
        else         w0 = W_in[(k0 - NU) * NU + u] * M_in[(k0 - NU) * NU + u];
        if (k1 < NU) w1 = W_rec[k1 * NU + u] * M_rec[k1 * NU + u];
        else         w1 = W_in[(k1 - NU) * NU + u] * M_in[(k1 - NU) * NU + u];
        h16x2 t; t[0] = (h16)w0; t[1] = (h16)w1;
        w[j] = t;
    }
    const float breg = (tid < NU) ? bias[u] : 0.0f;
    const long xbase = (long)b * SL * NC;

    if (tid < NU) vec[tid] = (h16)0.f;
    else if (tid < NU + NC) vec[tid] = (h16)x[xbase + (tid - NU)];
    __syncthreads();

    const bool xthr = (tid >= NU) && (tid < NU + NC);
    for (int t = 0; t < SL; ++t) {
        float xr = 0.f;
        if (xthr && (t + 1 < SL)) xr = x[xbase + (long)(t + 1) * NC + (tid - NU)];

        const h16x2* v2 = (const h16x2*)(&vec[ks]);
        float acc = 0.f;
#pragma unroll
        for (int j = 0; j < 48; ++j) acc = fdot2f(v2[j], w[j], acc);
        partial[kc][u] = acc;
        __syncthreads();

        if (tid < NU) {
            float s = partial[0][u] + partial[1][u] + partial[2][u] + partial[3][u] + breg;
            float hn = ftanh(s);
            vec[u] = (h16)hn;
            if (u >= NU - NO) out[((long)b * SL + t) * NO + (u - (NU - NO))] = hn;
            if (t == SL - 1)  out[(long)NB * SL * NO + (long)b * NU + u] = hn;
        } else if (xthr && (t + 1 < SL)) {
            vec[tid] = (h16)xr;
        }
        __syncthreads();
    }
}

extern "C" void kernel_launch(void* const* d_in, const int* in_sizes, int n_in,
                              void* d_out, int out_size, void* d_ws, size_t ws_size,
                              hipStream_t stream) {
    (void)in_sizes; (void)n_in; (void)out_size;
    const float* x     = (const float*)d_in[0];
    const float* W_in  = (const float*)d_in[1];
    const float* W_rec = (const float*)d_in[2];
    const float* bias  = (const float*)d_in[3];
    const float* M_in  = (const float*)d_in[4];
    const float* M_rec = (const float*)d_in[5];
    float* out = (float*)d_out;

    const size_t xw_bytes = (size_t)NB * SL * NU * sizeof(h16);   // 134,217,728
    if (ws_size >= xw_bytes) {
        h16* xw = (h16*)d_ws;
        xw_gemm_kernel<<<dim3((NB * SL) / GR), dim3(256), 0, stream>>>(x, W_in, bias, M_in, xw);
        rnn_scan_xw<<<dim3(NB), dim3(512), 0, stream>>>(W_rec, M_rec, xw, out);
    } else {
        rnn_scan_fallback<<<dim3(NB), dim3(1024), 0, stream>>>(x, W_in, W_rec, bias, M_in, M_rec, out);
    }
}

// Round 6
// 4265.651 us; speedup vs baseline: 1.2873x; 1.0624x over previous
//
#include <hip/hip_runtime.h>
#include <hip/hip_bf16.h>
#include <stdint.h>

// WiredRNN: h_{t+1} = tanh([h_t | x_t] @ [Wr;Wi] + b), B=32, L=8192, C=128, U=256, OUT=64.
// R8: scan is LDS-BANDWIDTH-bound (131 KB/step/CU = ~1030cy floor; matches R4/R5/R7 within
// 10%). Fix: each thread now owns 4 u's x 32 k's (was 1 u x 128 k) -> vec read traffic
// 131KB -> 32KB/step. vec stored transposed [q][kc][e] so the 8 kc-chunks tile each 128B
// LDS row -> conflict-free b128 reads. Cross-kc reduce (8 lanes, 4 values) via
// reduce-scatter: xor1/xor2 as DPP quad_perm (VALU pipe), xor4 as one ds_swizzle.
// kc<4 lanes write state; kc==7 lanes (u=G+192) write readout. xw chunk staging + single
// __syncthreads per step kept from R7.
// Fallback (ws_size too small): R3's proven K=384 scan.

#define NB 32
#define SL 8192
#define NC 128
#define NU 256
#define NO 64
#define NK 384
#define GR 64          // rows per GEMM workgroup
#define TC 16          // scan steps per xw chunk
#define NCHUNK (SL / TC)

typedef _Float16 h16;
typedef __attribute__((ext_vector_type(2))) _Float16 h16x2;

__device__ __forceinline__ float fdot2f(h16x2 a, h16x2 b, float c) {
#if __has_builtin(__builtin_amdgcn_fdot2)
    return __builtin_amdgcn_fdot2(a, b, c, false);
#else
    return c + (float)a[0] * (float)b[0] + (float)a[1] * (float)b[1];
#endif
}

// tanh(x) = 1 - 2/(e^{2x}+1);  e^{2x} = 2^{x*2*log2(e)}.  v_exp_f32 + v_rcp_f32.
__device__ __forceinline__ float ftanh(float x) {
#if __has_builtin(__builtin_amdgcn_exp2f) && __has_builtin(__builtin_amdgcn_rcpf)
    float e = __builtin_amdgcn_exp2f(x * 2.8853900817779268f);
    return 1.0f - 2.0f * __builtin_amdgcn_rcpf(e + 1.0f);
#else
    return tanhf(x);
#endif
}

// lane^1 exchange via DPP quad_perm [1,0,3,2] (VALU pipe, no LDS)
__device__ __forceinline__ float xor1f(float x) {
#if __has_builtin(__builtin_amdgcn_update_dpp)
    return __int_as_float(__builtin_amdgcn_update_dpp(0, __float_as_int(x), 0xB1, 0xF, 0xF, false));
#else
    return __shfl_xor(x, 1, 64);
#endif
}
// lane^2 exchange via DPP quad_perm [2,3,0,1]
__device__ __forceinline__ float xor2f(float x) {
#if __has_builtin(__builtin_amdgcn_update_dpp)
    return __int_as_float(__builtin_amdgcn_update_dpp(0, __float_as_int(x), 0x4E, 0xF, 0xF, false));
#else
    return __shfl_xor(x, 2, 64);
#endif
}
// lane^4 exchange via ds_swizzle (xor_mask=4, and_mask=0x1F)
__device__ __forceinline__ float xor4f(float x) {
#if __has_builtin(__builtin_amdgcn_ds_swizzle)
    return __int_as_float(__builtin_amdgcn_ds_swizzle(__float_as_int(x), 0x101F));
#else
    return __shfl_xor(x, 4, 64);
#endif
}

// ---------------- XW precompute GEMM ----------------
__global__ __launch_bounds__(256, 4) void xw_gemm_kernel(
    const float* __restrict__ x,      // [B*SL, NC]
    const float* __restrict__ W_in,   // [NC, NU]
    const float* __restrict__ bias,   // [NU]
    const float* __restrict__ M_in,   // [NC, NU]
    h16* __restrict__ xw)             // [B*SL, NU]
{
    const int u = threadIdx.x;
    const long row0 = (long)blockIdx.x * GR;
    __shared__ h16 xs[GR * NC];       // 16 KB

    for (int i = u; i < GR * NC; i += 256)
        xs[i] = (h16)x[row0 * NC + i];

    h16x2 wc[NC / 2];
#pragma unroll
    for (int j = 0; j < NC / 2; ++j) {
        const int k0 = 2 * j, k1 = 2 * j + 1;
        float w0 = W_in[k0 * NU + u] * M_in[k0 * NU + u];
        float w1 = W_in[k1 * NU + u] * M_in[k1 * NU + u];
        h16x2 t; t[0] = (h16)w0; t[1] = (h16)w1;
        wc[j] = t;
    }
    const float bs = bias[u];
    __syncthreads();

    for (int r = 0; r < GR; ++r) {
        const h16x2* xv = (const h16x2*)&xs[r * NC];
        float a0 = bs, a1 = 0.f, a2 = 0.f, a3 = 0.f;
#pragma unroll
        for (int j = 0; j < 16; ++j) {
            a0 = fdot2f(xv[4 * j + 0], wc[4 * j + 0], a0);
            a1 = fdot2f(xv[4 * j + 1], wc[4 * j + 1], a1);
            a2 = fdot2f(xv[4 * j + 2], wc[4 * j + 2], a2);
            a3 = fdot2f(xv[4 * j + 3], wc[4 * j + 3], a3);
        }
        xw[(row0 + r) * NU + u] = (h16)((a0 + a1) + (a2 + a3));
    }
}

// ---------------- recurrent scan (512 thr, 4u x 32k per thread, 1 barrier/step) ------------
// vec physical layout: logical k (bits [kc(3)|q(2)|e(3)]) stored at phys q*64 + kc*8 + e.
// Thread (wv, g=lane>>3, kc=lane&7) owns u = G + 64j (G = wv*8+g, j=0..3), k in [kc*32,+32).
__global__ __launch_bounds__(512, 2) void rnn_scan_xw(
    const float* __restrict__ W_rec,  // [NU, NU]
    const float* __restrict__ M_rec,  // [NU, NU]
    const h16* __restrict__ xw,       // [B*SL, NU] (bias folded in)
    float* __restrict__ out)          // [B*SL*NO] readout ++ [B*NU] h_last
{
    const int tid  = threadIdx.x;
    const int b    = blockIdx.x;
    const int lane = tid & 63;
    const int wv   = tid >> 6;            // 0..7
    const int kc   = lane & 7;            // k-chunk
    const int g    = lane >> 3;           // 0..7
    const int G    = (wv << 3) | g;       // 0..63

    __shared__ __align__(16) h16 vec[2][NU];         // transposed h state (1 KB)
    __shared__ __align__(16) h16 xwc[2][TC][NU];     // double-buffered xw chunks (16 KB)

    // weights w[j][q*4+ep] = Wr_masked[k = kc*32 + q*8 + 2ep][u = G + 64j], f16 pairs (64 VGPR)
    h16x2 w[4][16];
#pragma unroll
    for (int j = 0; j < 4; ++j) {
        const int u = G + 64 * j;
#pragma unroll
        for (int q = 0; q < 4; ++q)
#pragma unroll
            for (int ep = 0; ep < 4; ++ep) {
                const int k0 = kc * 32 + q * 8 + 2 * ep;
                float w0 = W_rec[k0 * NU + u] * M_rec[k0 * NU + u];
                float w1 = W_rec[(k0 + 1) * NU + u] * M_rec[(k0 + 1) * NU + u];
                h16x2 t; t[0] = (h16)w0; t[1] = (h16)w1;
                w[j][q * 4 + ep] = t;
            }
    }

    // after reduce-scatter, this lane holds u_mine = G + 64*j_of (duplicated across kc^4)
    const int  j_of    = 2 * (kc & 1) + ((kc >> 1) & 1);
    const int  u_mine  = G + 64 * j_of;
    const bool writer  = (kc < 4);                 // one lane per u writes state
    const bool reader  = (kc == 7);                // u_mine = G+192 -> readout lane
    // phys index of u_mine in vec layout
    const int  pidx    = ((u_mine >> 3) & 3) * 64 + (u_mine >> 5) * 8 + (u_mine & 7);

    const h16* __restrict__ xwb = xw + (long)b * SL * NU;
    float* const outb = out + (long)b * SL * NO;

    // prologue: chunk 0 -> LDS buffer 0; h0 = 0
    {
        const int4 c0 = ((const int4*)xwb)[tid];
        if (tid < NU) vec[0][tid] = (h16)0.f;
        ((int4*)&xwc[0][0][0])[tid] = c0;
        __syncthreads();
    }

    for (int tc = 0; tc < NCHUNK; ++tc) {
        const int cb = tc & 1;
        const bool havenext = (tc + 1 < NCHUNK);
        int4 creg;
        if (havenext)
            creg = ((const int4*)(xwb + (long)(tc + 1) * TC * NU))[tid];
        float sbuf[TC];                            // statically indexed (full unroll)

#pragma unroll
        for (int j = 0; j < TC; ++j) {
            const float xwv = (float)xwc[cb][j][u_mine];   // issued early, used after reduce

            // 4 x ds_read_b128 (conflict-free: 8 kc-chunks tile each 128B row)
            const h16x2* v2 = (const h16x2*)&vec[j & 1][0] + (kc << 2);
            float acc0 = 0.f, acc1 = 0.f, acc2 = 0.f, acc3 = 0.f;
#pragma unroll
            for (int q = 0; q < 4; ++q) {
                const h16x2 x0 = v2[q * 32 + 0], x1 = v2[q * 32 + 1];
                const h16x2 x2 = v2[q * 32 + 2], x3 = v2[q * 32 + 3];
                acc0 = fdot2f(x0, w[0][q*4+0], acc0); acc0 = fdot2f(x1, w[0][q*4+1], acc0);
                acc0 = fdot2f(x2, w[0][q*4+2], acc0); acc0 = fdot2f(x3, w[0][q*4+3], acc0);
                acc1 = fdot2f(x0, w[1][q*4+0], acc1); acc1 = fdot2f(x1, w[1][q*4+1], acc1);
                acc1 = fdot2f(x2, w[1][q*4+2], acc1); acc1 = fdot2f(x3, w[1][q*4+3], acc1);
                acc2 = fdot2f(x0, w[2][q*4+0], acc2); acc2 = fdot2f(x1, w[2][q*4+1], acc2);
                acc2 = fdot2f(x2, w[2][q*4+2], acc2); acc2 = fdot2f(x3, w[2][q*4+3], acc2);
                acc3 = fdot2f(x0, w[3][q*4+0], acc3); acc3 = fdot2f(x1, w[3][q*4+1], acc3);
                acc3 = fdot2f(x2, w[3][q*4+2], acc3); acc3 = fdot2f(x3, w[3][q*4+3], acc3);
            }

            // reduce-scatter over the 8 kc lanes (4 values -> 1 per lane, dup over kc^4)
            // R1 (xor1, DPP): even kc keeps j0,j1; odd keeps j2,j3
            const bool o1 = (kc & 1);
            float s0 = o1 ? acc0 : acc2;
            float s1 = o1 ? acc1 : acc3;
            float q0 = (o1 ? acc2 : acc0) + xor1f(s0);
            float q1 = (o1 ? acc3 : acc1) + xor1f(s1);
            // R2 (xor2, DPP)
            const bool o2 = (kc & 2);
            float s2 = o2 ? q0 : q1;
            float v  = (o2 ? q1 : q0) + xor2f(s2);
            // R3 (xor4, ds_swizzle): full k sum; lanes kc and kc^4 now duplicate u_mine
            const float total = v + xor4f(v);

            const float hn = ftanh(total + xwv);
            if (writer) vec[(j + 1) & 1][pidx] = (h16)hn;  // state into next buffer
            sbuf[j] = hn;

            if (j == TC - 1) {
                if (havenext) ((int4*)&xwc[cb ^ 1][0][0])[tid] = creg;
                if (reader) {                      // u_mine = G+192: readout flush
#pragma unroll
                    for (int jj = 0; jj < TC; ++jj)
                        outb[(long)(tc * TC + jj) * NO + G] = sbuf[jj];
                }
                if (writer && tc == NCHUNK - 1)
                    out[(long)NB * SL * NO + (long)b * NU + u_mine] = hn;   // h_last
            }
            __syncthreads();                       // ONE barrier/step
        }
    }
}

// ---------------- fallback (R3, proven): K=384 scan reading x directly ----------------
__global__ __launch_bounds__(1024, 4) void rnn_scan_fallback(
    const float* __restrict__ x,
    const float* __restrict__ W_in,
    const float* __restrict__ W_rec,
    const float* __restrict__ bias,
    const float* __restrict__ M_in,
    const float* __restrict__ M_rec,
    float* __restrict__ out)
{
    const int tid = threadIdx.x;
    const int b   = blockIdx.x;
    const int u   = tid & (NU - 1);
    const int kc  = tid >> 8;
    const int ks  = kc * 96;

    __shared__ __align__(16) h16 vec[NK];
    __shared__ float partial[4][NU];

    h16x2 w[48];
#pragma unroll
    for (int j = 0; j < 48; ++j) {
        const int k0 = ks + 2 * j, k1 = k0 + 1;
        float w0, w1;
        if (k0 < NU) w0 = W_rec[k0 * NU + u] * M_rec[k0 * NU + u];
        else         w0 = W_in[(k0 - NU) * NU + u] * M_in[(k0 - NU) * NU + u];
        if (k1 < NU) w1 = W_rec[k1 * NU + u] * M_rec[k1 * NU + u];
        else         w1 = W_in[(k1 - NU) * NU + u] * M_in[(k1 - NU) * NU + u];
        h16x2 t; t[0] = (h16)w0; t[1] = (h16)w1;
        w[j] = t;
    }
    const float breg = (tid < NU) ? bias[u] : 0.0f;
    const long xbase = (long)b * SL * NC;

    if (tid < NU) vec[tid] = (h16)0.f;
    else if (tid < NU + NC) vec[tid] = (h16)x[xbase + (tid - NU)];
    __syncthreads();

    const bool xthr = (tid >= NU) && (tid < NU + NC);
    for (int t = 0; t < SL; ++t) {
        float xr = 0.f;
        if (xthr && (t + 1 < SL)) xr = x[xbase + (long)(t + 1) * NC + (tid - NU)];

        const h16x2* v2 = (const h16x2*)(&vec[ks]);
        float acc = 0.f;
#pragma unroll
        for (int j = 0; j < 48; ++j) acc = fdot2f(v2[j], w[j], acc);
        partial[kc][u] = acc;
        __syncthreads();

        if (tid < NU) {
            float s = partial[0][u] + partial[1][u] + partial[2][u] + partial[3][u] + breg;
            float hn = ftanh(s);
            vec[u] = (h16)hn;
            if (u >= NU - NO) out[((long)b * SL + t) * NO + (u - (NU - NO))] = hn;
            if (t == SL - 1)  out[(long)NB * SL * NO + (long)b * NU + u] = hn;
        } else if (xthr && (t + 1 < SL)) {
            vec[tid] = (h16)xr;
        }
        __syncthreads();
    }
}

extern "C" void kernel_launch(void* const* d_in, const int* in_sizes, int n_in,
                              void* d_out, int out_size, void* d_ws, size_t ws_size,
                              hipStream_t stream) {
    (void)in_sizes; (void)n_in; (void)out_size;
    const float* x     = (const float*)d_in[0];
    const float* W_in  = (const float*)d_in[1];
    const float* W_rec = (const float*)d_in[2];
    const float* bias  = (const float*)d_in[3];
    const float* M_in  = (const float*)d_in[4];
    const float* M_rec = (const float*)d_in[5];
    float* out = (float*)d_out;

    const size_t xw_bytes = (size_t)NB * SL * NU * sizeof(h16);   // 134,217,728
    if (ws_size >= xw_bytes) {
        h16* xw = (h16*)d_ws;
        xw_gemm_kernel<<<dim3((NB * SL) / GR), dim3(256), 0, stream>>>(x, W_in, bias, M_in, xw);
        rnn_scan_xw<<<dim3(NB), dim3(512), 0, stream>>>(W_rec, M_rec, xw, out);
    } else {
        rnn_scan_fallback<<<dim3(NB), dim3(1024), 0, stream>>>(x, W_in, W_rec, bias, M_in, M_rec, out);
    }
}

// Round 7
// 4086.220 us; speedup vs baseline: 1.3438x; 1.0439x over previous
//
#include <hip/hip_runtime.h>
#include <hip/hip_bf16.h>
#include <stdint.h>

// WiredRNN: h_{t+1} = tanh([h_t | x_t] @ [Wr;Wi] + b), B=32, L=8192, C=128, U=256, OUT=64.
// R9: R8 post-mortem showed VALU-overhead bound (61% VALU-busy on active CUs; fdot2 floor is
// only 256cy/SIMD/step of the 1146cy step). R9 keeps R8's 4u x 32k decomposition and:
//   a) SELECT-FREE reduce: weight slots pre-permuted per kc so reduce-scatter is
//      q0=a0+xor1(a2); q1=a1+xor1(a3); v=q0+xor2(q1); tot=v+xor4(v) - no cndmasks.
//   b) forced b128 vec reads (uint4 + bit_cast), compile-time LDS offsets off 2 base ptrs.
//   c) xw rows stored in the scan's phys (pidx) layout by the GEMM -> conflict-free xw
//      reads + state writes (kills R8's 1.26e7 bank conflicts); xw[j+1] prefetched in step j.
// Fallback (ws_size too small): R3's proven K=384 scan (does not use xw/layout).

#define NB 32
#define SL 8192
#define NC 128
#define NU 256
#define NO 64
#define NK 384
#define GR 64          // rows per GEMM workgroup
#define TC 16          // scan steps per xw chunk
#define NCHUNK (SL / TC)

typedef _Float16 h16;
typedef __attribute__((ext_vector_type(2))) _Float16 h16x2;

__device__ __forceinline__ float fdot2f(h16x2 a, h16x2 b, float c) {
#if __has_builtin(__builtin_amdgcn_fdot2)
    return __builtin_amdgcn_fdot2(a, b, c, false);
#else
    return c + (float)a[0] * (float)b[0] + (float)a[1] * (float)b[1];
#endif
}

// tanh(x) = 1 - 2/(e^{2x}+1);  e^{2x} = 2^{x*2*log2(e)}.  v_exp_f32 + v_rcp_f32.
__device__ __forceinline__ float ftanh(float x) {
#if __has_builtin(__builtin_amdgcn_exp2f) && __has_builtin(__builtin_amdgcn_rcpf)
    float e = __builtin_amdgcn_exp2f(x * 2.8853900817779268f);
    return 1.0f - 2.0f * __builtin_amdgcn_rcpf(e + 1.0f);
#else
    return tanhf(x);
#endif
}

// lane^1 exchange via DPP quad_perm [1,0,3,2] (VALU pipe, no LDS)
__device__ __forceinline__ float xor1f(float x) {
#if __has_builtin(__builtin_amdgcn_update_dpp)
    return __int_as_float(__builtin_amdgcn_update_dpp(0, __float_as_int(x), 0xB1, 0xF, 0xF, false));
#else
    return __shfl_xor(x, 1, 64);
#endif
}
// lane^2 exchange via DPP quad_perm [2,3,0,1]
__device__ __forceinline__ float xor2f(float x) {
#if __has_builtin(__builtin_amdgcn_update_dpp)
    return __int_as_float(__builtin_amdgcn_update_dpp(0, __float_as_int(x), 0x4E, 0xF, 0xF, false));
#else
    return __shfl_xor(x, 2, 64);
#endif
}
// lane^4 exchange via ds_swizzle (xor_mask=4, and_mask=0x1F)
__device__ __forceinline__ float xor4f(float x) {
#if __has_builtin(__builtin_amdgcn_ds_swizzle)
    return __int_as_float(__builtin_amdgcn_ds_swizzle(__float_as_int(x), 0x101F));
#else
    return __shfl_xor(x, 4, 64);
#endif
}

// phys position of unit u in the transposed state/xw layout:
// logical k bits [kc(3)|q(2)|e(3)] stored at phys q*64 + kc*8 + e
__device__ __host__ __forceinline__ int physidx(int u) {
    return ((u >> 3) & 3) * 64 + (u >> 5) * 8 + (u & 7);
}

// ---------------- XW precompute GEMM (writes rows in pidx layout) ----------------
__global__ __launch_bounds__(256, 4) void xw_gemm_kernel(
    const float* __restrict__ x,      // [B*SL, NC]
    const float* __restrict__ W_in,   // [NC, NU]
    const float* __restrict__ bias,   // [NU]
    const float* __restrict__ M_in,   // [C, NU]
    h16* __restrict__ xw)             // [B*SL, NU] (row-permuted by physidx)
{
    const int u = threadIdx.x;
    const long row0 = (long)blockIdx.x * GR;
    __shared__ h16 xs[GR * NC];       // 16 KB

    for (int i = u; i < GR * NC; i += 256)
        xs[i] = (h16)x[row0 * NC + i];

    h16x2 wc[NC / 2];
#pragma unroll
    for (int j = 0; j < NC / 2; ++j) {
        const int k0 = 2 * j, k1 = 2 * j + 1;
        float w0 = W_in[k0 * NU + u] * M_in[k0 * NU + u];
        float w1 = W_in[k1 * NU + u] * M_in[k1 * NU + u];
        h16x2 t; t[0] = (h16)w0; t[1] = (h16)w1;
        wc[j] = t;
    }
    const float bs = bias[u];
    const int pu = physidx(u);
    __syncthreads();

    for (int r = 0; r < GR; ++r) {
        const h16x2* xv = (const h16x2*)&xs[r * NC];
        float a0 = bs, a1 = 0.f, a2 = 0.f, a3 = 0.f;
#pragma unroll
        for (int j = 0; j < 16; ++j) {
            a0 = fdot2f(xv[4 * j + 0], wc[4 * j + 0], a0);
            a1 = fdot2f(xv[4 * j + 1], wc[4 * j + 1], a1);
            a2 = fdot2f(xv[4 * j + 2], wc[4 * j + 2], a2);
            a3 = fdot2f(xv[4 * j + 3], wc[4 * j + 3], a3);
        }
        xw[(row0 + r) * NU + pu] = (h16)((a0 + a1) + (a2 + a3));
    }
}

// ---------------- recurrent scan (512 thr, select-free reduce, 1 barrier/step) -------------
// Thread (wv, g=lane>>3, kc=lane&7): G = wv*8+g; computes 4 u's (slot s -> u = G+64*ord[s],
// ord[s] = j_of((kc&3)^P[s]), P={0,2,1,3}, j_of(m)=2*(m&1)+((m>>1)&1)) over k in [kc*32,+32).
__global__ __launch_bounds__(512, 2) void rnn_scan_xw(
    const float* __restrict__ W_rec,  // [NU, NU]
    const float* __restrict__ M_rec,  // [NU, NU]
    const h16* __restrict__ xw,       // [B*SL, NU] (bias folded in; pidx row layout)
    float* __restrict__ out)          // [B*SL*NO] readout ++ [B*NU] h_last
{
    const int tid  = threadIdx.x;
    const int b    = blockIdx.x;
    const int lane = tid & 63;
    const int wv   = tid >> 6;            // 0..7
    const int kc   = lane & 7;            // k-chunk
    const int g    = lane >> 3;           // 0..7
    const int G    = (wv << 3) | g;       // 0..63

    __shared__ __align__(16) h16 vec[2][NU];         // transposed h state (1 KB)
    __shared__ __align__(16) h16 xwc[2][TC][NU];     // double-buffered xw chunks (16 KB)

    // slot->j mapping (select-free reduce)
    int ord[4];
    {
        const int m = kc & 3;
        const int P[4] = {0, 2, 1, 3};
#pragma unroll
        for (int s = 0; s < 4; ++s) {
            const int mm = m ^ P[s];
            ord[s] = 2 * (mm & 1) + ((mm >> 1) & 1);
        }
    }

    // masked recurrent weights: slot s holds u = G + 64*ord[s], k = kc*32 + q*8 + 2ep(+1)
    h16x2 w[4][16];
#pragma unroll
    for (int s = 0; s < 4; ++s) {
        const int u = G + 64 * ord[s];
#pragma unroll
        for (int q = 0; q < 4; ++q)
#pragma unroll
            for (int ep = 0; ep < 4; ++ep) {
                const int k0 = kc * 32 + q * 8 + 2 * ep;
                float w0 = W_rec[k0 * NU + u] * M_rec[k0 * NU + u];
                float w1 = W_rec[(k0 + 1) * NU + u] * M_rec[(k0 + 1) * NU + u];
                h16x2 t; t[0] = (h16)w0; t[1] = (h16)w1;
                w[s][q * 4 + ep] = t;
            }
    }

    const int  u_mine = G + 64 * ord[0];           // final owner after reduce (dup over kc^4)
    const bool writer = (kc < 4);                  // kc 0..3 cover all 4 j's exactly once
    const bool reader = (kc == 7);                 // ord[0](7)=3 -> u_mine = G+192 (motor)
    const int  pidx   = physidx(u_mine);

    // precomputed LDS base pointers (all loop offsets become immediates)
    const char* vb0 = (const char*)&vec[0][0] + (kc << 4);   // read base, buffer 0
    const char* vb1 = vb0 + 512;                             // buffer 1 (+256 h16)
    h16* const wp0 = &vec[0][pidx];                          // write ptr, buffer 0
    h16* const wp1 = (h16*)((char*)wp0 + 512);               // buffer 1
    const h16* const xcA = &xwc[0][0][pidx];
    const h16* const xcB = xcA + TC * NU;

    const h16* __restrict__ xwb = xw + (long)b * SL * NU;
    float* const outb = out + (long)b * SL * NO;

    // prologue: chunk 0 -> LDS buffer 0; h0 = 0
    {
        const int4 c0 = ((const int4*)xwb)[tid];
        if (tid < NU) vec[0][tid] = (h16)0.f;
        ((int4*)&xwc[0][0][0])[tid] = c0;
        __syncthreads();
    }

    for (int tc = 0; tc < NCHUNK; ++tc) {
        const int cb = tc & 1;
        const bool havenext = (tc + 1 < NCHUNK);
        const h16* xc = cb ? xcB : xcA;            // this chunk's xw base (+pidx)
        int4* pk = (int4*)&xwc[cb ^ 1][0][0] + tid;
        int4 creg;
        if (havenext)
            creg = ((const int4*)(xwb + (long)(tc + 1) * TC * NU))[tid];
        float sbuf[TC];                            // statically indexed (full unroll)

        float xwv = (float)xc[0];                  // xw for step 0 of this chunk

#pragma unroll
        for (int j = 0; j < TC; ++j) {
            // prefetch next step's xw from LDS (overlaps the dot)
            float xwn = 0.f;
            if (j + 1 < TC) xwn = (float)xc[(j + 1) * NU];

            // 4 forced-b128 reads; all offsets compile-time
            const char* vb = (j & 1) ? vb1 : vb0;
            float a0 = 0.f, a1 = 0.f, a2 = 0.f, a3 = 0.f;
#pragma unroll
            for (int q = 0; q < 4; ++q) {
                const uint4 blk = *(const uint4*)(vb + q * 128);
                const h16x2 x0 = __builtin_bit_cast(h16x2, blk.x);
                const h16x2 x1 = __builtin_bit_cast(h16x2, blk.y);
                const h16x2 x2 = __builtin_bit_cast(h16x2, blk.z);
                const h16x2 x3 = __builtin_bit_cast(h16x2, blk.w);
                a0 = fdot2f(x0, w[0][q*4+0], a0); a0 = fdot2f(x1, w[0][q*4+1], a0);
                a0 = fdot2f(x2, w[0][q*4+2], a0); a0 = fdot2f(x3, w[0][q*4+3], a0);
                a1 = fdot2f(x0, w[1][q*4+0], a1); a1 = fdot2f(x1, w[1][q*4+1], a1);
                a1 = fdot2f(x2, w[1][q*4+2], a1); a1 = fdot2f(x3, w[1][q*4+3], a1);
                a2 = fdot2f(x0, w[2][q*4+0], a2); a2 = fdot2f(x1, w[2][q*4+1], a2);
                a2 = fdot2f(x2, w[2][q*4+2], a2); a2 = fdot2f(x3, w[2][q*4+3], a2);
                a3 = fdot2f(x0, w[3][q*4+0], a3); a3 = fdot2f(x1, w[3][q*4+1], a3);
                a3 = fdot2f(x2, w[3][q*4+2], a3); a3 = fdot2f(x3, w[3][q*4+3], a3);
            }

            // select-free reduce-scatter (slots pre-permuted per kc)
            const float q0  = a0 + xor1f(a2);
            const float q1  = a1 + xor1f(a3);
            const float v   = q0 + xor2f(q1);
            const float tot = v + xor4f(v) + xwv;

            const float hn = ftanh(tot);
            if (writer) {
                h16* wp = (j & 1) ? wp0 : wp1;     // step j writes buffer (j+1)&1
                *wp = (h16)hn;
            }
            sbuf[j] = hn;

            if (j == TC - 1) {
                if (havenext) *pk = creg;          // park next chunk (vmcnt long satisfied)
                if (reader) {                      // u_mine = G+192: readout flush
#pragma unroll
                    for (int jj = 0; jj < TC; ++jj)
                        outb[(long)(tc * TC + jj) * NO + G] = sbuf[jj];
                }
                if (writer && tc == NCHUNK - 1)
                    out[(long)NB * SL * NO + (long)b * NU + u_mine] = hn;   // h_last
            }
            __syncthreads();                       // ONE barrier/step
            xwv = xwn;
        }
    }
}

// ---------------- fallback (R3, proven): K=384 scan reading x directly ----------------
__global__ __launch_bounds__(1024, 4) void rnn_scan_fallback(
    const float* __restrict__ x,
    const float* __restrict__ W_in,
    const float* __restrict__ W_rec,
    const float* __restrict__ bias,
    const float* __restrict__ M_in,
    const float* __restrict__ M_rec,
    float* __restrict__ out)
{
    const int tid = threadIdx.x;
    const int b   = blockIdx.x;
    const int u   = tid & (NU - 1);
    const int kc  = tid >> 8;
    const int ks  = kc * 96;

    __shared__ __align__(16) h16 vec[NK];
    __shared__ float partial[4][NU];

    h16x2 w[48];
#pragma unroll
    for (int j = 0; j < 48; ++j) {
        const int k0 = ks + 2 * j, k1 = k0 + 1;
        float w0, w1;
        if (k0 < NU) w0 = W_rec[k0 * NU + u] * M_rec[k0 * NU + u];
        else         w0 = W_in[(k0 - NU) * NU + u] * M_in[(k0 - NU) * NU + u];
        if (k1 < NU) w1 = W_rec[k1 * NU + u] * M_rec[k1 * NU + u];
        else         w1 = W_in[(k1 - NU) * NU + u] * M_in[(k1 - NU) * NU + u];
        h16x2 t; t[0] = (h16)w0; t[1] = (h16)w1;
        w[j] = t;
    }
    const float breg = (tid < NU) ? bias[u] : 0.0f;
    const long xbase = (long)b * SL * NC;

    if (tid < NU) vec[tid] = (h16)0.f;
    else if (tid < NU + NC) vec[tid] = (h16)x[xbase + (tid - NU)];
    __syncthreads();

    const bool xthr = (tid >= NU) && (tid < NU + NC);
    for (int t = 0; t < SL; ++t) {
        float xr = 0.f;
        if (xthr && (t + 1 < SL)) xr = x[xbase + (long)(t + 1) * NC + (tid - NU)];

        const h16x2* v2 = (const h16x2*)(&vec[ks]);
        float acc = 0.f;
#pragma unroll
        for (int j = 0; j < 48; ++j) acc = fdot2f(v2[j], w[j], acc);
        partial[kc][u] = acc;
        __syncthreads();

        if (tid < NU) {
            float s = partial[0][u] + partial[1][u] + partial[2][u] + partial[3][u] + breg;
            float hn = ftanh(s);
            vec[u] = (h16)hn;
            if (u >= NU - NO) out[((long)b * SL + t) * NO + (u - (NU - NO))] = hn;
            if (t == SL - 1)  out[(long)NB * SL * NO + (long)b * NU + u] = hn;
        } else if (xthr && (t + 1 < SL)) {
            vec[tid] = (h16)xr;
        }
        __syncthreads();
    }
}

extern "C" void kernel_launch(void* const* d_in, const int* in_sizes, int n_in,
                              void* d_out, int out_size, void* d_ws, size_t ws_size,
                              hipStream_t stream) {
    (void)in_sizes; (void)n_in; (void)out_size;
    const float* x     = (const float*)d_in[0];
    const float* W_in  = (const float*)d_in[1];
    const float* W_rec = (const float*)d_in[2];
    const float* bias  = (const float*)d_in[3];
    const float* M_in  = (const float*)d_in[4];
    const float* M_rec = (const float*)d_in[5];
    float* out = (float*)d_out;

    const size_t xw_bytes = (size_t)NB * SL * NU * sizeof(h16);   // 134,217,728
    if (ws_size >= xw_bytes) {
        h16* xw = (h16*)d_ws;
        xw_gemm_kernel<<<dim3((NB * SL) / GR), dim3(256), 0, stream>>>(x, W_in, bias, M_in, xw);
        rnn_scan_xw<<<dim3(NB), dim3(512), 0, stream>>>(W_rec, M_rec, xw, out);
    } else {
        rnn_scan_fallback<<<dim3(NB), dim3(1024), 0, stream>>>(x, W_in, W_rec, bias, M_in, M_rec, out);
    }
}